// Round 1
// 524.984 us; speedup vs baseline: 1.0398x; 1.0398x over previous
//
#include <hip/hip_runtime.h>
#include <math.h>

// Problem constants
#define TT 8
#define FN 2304          // 48*48
#define FL 1024          // C*S*S
#define HS 48

typedef __attribute__((ext_vector_type(8))) short short8;
typedef __attribute__((ext_vector_type(4))) float floatx4;

// ---------------- workspace layout (bytes) ----------------
// idx1t stays live through k_mat (tk is eliminated); old tk region hosts the
// late-phase aliases (sel / fin / wb) plus the small norm/indirection arrays.
static constexpr size_t OFF_IDX1T  = 0;                       // 75,497,472 (live until k_mat done)
static constexpr size_t OFF_SEL    = 75497472;                // 28,311,552 (written by k_sel, after k_mat)
static constexpr size_t OFF_FIN    = 103809024;               // 14,451,072 bf16 conv input
static constexpr size_t OFF_WB     = 132713472;               // 221,184 bf16 weights
static constexpr size_t OFF_NORM2  = 135497472;               // 73,728
static constexpr size_t OFF_PSRC   = 135571200;               // 73,728
static constexpr size_t OFF_PSCALE = 135644928;               // 73,728
static constexpr size_t OFF_CN     = 150994944;               // 9,437,184
static constexpr size_t OFF_QH     = 160432128;               // 4,718,592
static constexpr size_t OFF_SRCMAP = 165150720;               // 73,728
static constexpr size_t OFF_BSRC   = 165224448;               // 1,179,648
static constexpr size_t OFF_BW     = 166404096;               // 1,179,648
static constexpr size_t OFF_CSOFT  = 167583744;               // 9,216
static constexpr size_t OFF_CIDX   = 167592960;               // 9,216
static constexpr size_t OFF_CSRC   = 167602176;               // 147,456
static constexpr size_t OFF_CW     = 167749632;               // 147,456  -> total 167,897,088

__device__ inline ushort f2bf(float x) {   // round-to-nearest-even f32->bf16
  union { float f; unsigned int u; } v; v.f = x;
  unsigned int r = (v.u + 0x7FFFu + ((v.u >> 16) & 1u)) >> 16;
  return (ushort)r;
}

// ---------------- K0: nearest-neighbor source map (+ zero norm2) ----------------
__global__ void k_nearmap(const float* __restrict__ loc, int* __restrict__ srcmap,
                          float* __restrict__ norm2) {
  int idx = blockIdx.x * 256 + threadIdx.x;
  if (idx >= TT * FN) return;
  norm2[idx] = 0.f;
  int t = idx / FN, f = idx % FN;
  float lx = loc[(size_t)(t * 2 + 0) * FN + f];
  float ly = loc[(size_t)(t * 2 + 1) * FN + f];
  float gx = 2.0f * lx / 47.0f - 1.0f;
  float gy = 2.0f * ly / 47.0f - 1.0f;
  float ix = (gx + 1.0f) * 0.5f * 47.0f;
  float iy = (gy + 1.0f) * 0.5f * 47.0f;
  int ixn = __float2int_rn(ix);
  int iyn = __float2int_rn(iy);
  bool valid = (ixn >= 0) && (ixn < 48) && (iyn >= 0) && (iyn < 48);
  srcmap[idx] = valid ? (iyn * 48 + ixn) : -1;
}

// ---------------- K1: transpose idx1 (t,cl,f) -> (t,f,cl) + row-norm accumulation ----------------
__global__ __launch_bounds__(256) void k_transpose(const float* __restrict__ in, float* __restrict__ out,
                                                   float* __restrict__ norm2) {
  __shared__ float tile[64][65];
  const int t = blockIdx.z;
  const int cl0 = blockIdx.x * 64;   // 16 tiles
  const int f0 = blockIdx.y * 64;    // 36 tiles
  const float* src = in + (size_t)t * FL * FN;
  float* dst = out + (size_t)t * FN * FL;
  const int tx = threadIdx.x & 15, ty = threadIdx.x >> 4;  // 16 x 16
#pragma unroll
  for (int k = 0; k < 4; k++) {
    const float4 v = *reinterpret_cast<const float4*>(src + (size_t)(cl0 + ty + 16 * k) * FN + f0 + tx * 4);
    float* tr = &tile[ty + 16 * k][tx * 4];
    tr[0] = v.x; tr[1] = v.y; tr[2] = v.z; tr[3] = v.w;
  }
  __syncthreads();
#pragma unroll
  for (int k = 0; k < 4; k++) {
    float4 v;
    v.x = tile[tx * 4 + 0][ty + 16 * k];
    v.y = tile[tx * 4 + 1][ty + 16 * k];
    v.z = tile[tx * 4 + 2][ty + 16 * k];
    v.w = tile[tx * 4 + 3][ty + 16 * k];
    *reinterpret_cast<float4*>(dst + (size_t)(f0 + ty + 16 * k) * FL + cl0 + tx * 4) = v;
    // per-f sum of squares over this 64-cl tile: reduce across the 16 tx lanes
    float ss = v.x * v.x + v.y * v.y + v.z * v.z + v.w * v.w;
    ss += __shfl_xor(ss, 1, 64);
    ss += __shfl_xor(ss, 2, 64);
    ss += __shfl_xor(ss, 4, 64);
    ss += __shfl_xor(ss, 8, 64);
    if (tx == 0) atomicAdd(&norm2[(size_t)t * FN + f0 + ty + 16 * k], ss);
  }
}

// ---------------- K1b: per-(t,f) clamped source row + L2-norm scale ----------------
__global__ void k_pos(const int* __restrict__ srcmap, const float* __restrict__ norm2,
                      int* __restrict__ psrc, float* __restrict__ pscale) {
  int idx = blockIdx.x * 256 + threadIdx.x;
  if (idx >= TT * FN) return;
  int s = srcmap[idx];
  int t = idx / FN;
  if (s < 0) {
    psrc[idx] = 0; pscale[idx] = 0.f;
  } else {
    psrc[idx] = s;
    float n2 = norm2[t * FN + s];
    pscale[idx] = 1.0f / fmaxf(sqrtf(n2), 1e-12f);
  }
}

// ---------------- K3: unfold curr_feat + L2-normalize -> cn (f,cl) ----------------
__global__ __launch_bounds__(256) void k_cn(const float* __restrict__ cf, float* __restrict__ cn) {
  __shared__ float red[4];
  int f = blockIdx.x;             // i*48+j
  int i = f / 48, j = f % 48;
  int tid = threadIdx.x;
  float v[4];
  float sq = 0.f;
#pragma unroll
  for (int k = 0; k < 4; k++) {
    int cl = tid + 256 * k;
    int c = cl >> 4, sy = (cl >> 2) & 3, sx = cl & 3;
    v[k] = cf[(size_t)c * 36864 + (size_t)(i * 4 + sy) * 192 + (j * 4 + sx)];
    sq += v[k] * v[k];
  }
#pragma unroll
  for (int m = 1; m <= 32; m <<= 1) sq += __shfl_xor(sq, m, 64);
  int lane = tid & 63, w = tid >> 6;
  if (lane == 0) red[w] = sq;
  __syncthreads();
  float total = red[0] + red[1] + red[2] + red[3];
  float scale = 1.0f / fmaxf(sqrtf(total), 1e-12f);
#pragma unroll
  for (int k = 0; k < 4; k++) cn[(size_t)f * FL + tid + 256 * k] = v[k] * scale;
}

// ---------------- K4: q-half grouped 5x5 conv (t-invariant, per g), XCD-swizzled ----------------
__global__ __launch_bounds__(128) void k_qconv(const float* __restrict__ cn,
                                               const float* __restrict__ wtdw,
                                               const float* __restrict__ btdw,
                                               float* __restrict__ qhalf) {
  // 576 blocks; plane g lives on XCD pair {2g,2g+1} so its 2.36 MB cn-slice stays L2-local
  const int i = blockIdx.x;
  const int xcd = i & 7;
  const int sl = i >> 3;             // 0..71
  const int g = xcd >> 1;
  const int r0 = (xcd & 1) * 72 + sl;  // 0..143
  const int y = r0 / 3;
  const int xt = r0 - y * 3;
  const int j = threadIdx.x;      // output channel 0..127
  const int x0 = xt * 16;
  float w0[25], w1[25];
  {
    const float* wp = wtdw + (size_t)j * 50;
#pragma unroll
    for (int p = 0; p < 25; ++p) { w0[p] = wp[p]; w1[p] = wp[25 + p]; }
  }
  float acc[16];
#pragma unroll
  for (int i2 = 0; i2 < 16; ++i2) acc[i2] = 0.f;
  const int cbase = g * 256 + 2 * j;
#pragma unroll
  for (int r = 0; r < 5; ++r) {
    const int yy = y - 2 + r;
    if (yy < 0 || yy >= 48) continue;
#pragma unroll
    for (int cc2 = 0; cc2 < 20; ++cc2) {
      const int xx = x0 - 2 + cc2;
      float vx = 0.f, vy = 0.f;
      if (xx >= 0 && xx < 48) {
        const float2 v = *reinterpret_cast<const float2*>(cn + ((size_t)(yy * 48 + xx) << 10) + cbase);
        vx = v.x; vy = v.y;
      }
#pragma unroll
      for (int kx = 0; kx < 5; ++kx) {
        const int xo = cc2 - kx;
        if (xo >= 0 && xo < 16)
          acc[xo] = fmaf(vx, w0[r * 5 + kx], fmaf(vy, w1[r * 5 + kx], acc[xo]));
      }
    }
  }
  const float bb = btdw[j];
#pragma unroll
  for (int xo = 0; xo < 16; ++xo)
    qhalf[((size_t)g * FN + (y * 48 + x0 + xo)) * 128 + j] = acc[xo] + bb;
}

// ---------------- K5: k-half conv (indirect from idx1t) + LN + GELU + 1x1 + tanh + refpts ----------------
__global__ __launch_bounds__(128) void k_kconv_ln(const float* __restrict__ idx1t,
                                                  const int* __restrict__ psrc,
                                                  const float* __restrict__ pscale,
                                                  const float* __restrict__ wtdw,
                                                  const float* __restrict__ btdw,
                                                  const float* __restrict__ qhalf,
                                                  const float* __restrict__ lng,
                                                  const float* __restrict__ lnb,
                                                  const float* __restrict__ wtpw,
                                                  int* __restrict__ bsrc,
                                                  float* __restrict__ bw) {
  __shared__ float ch[16][257];
  __shared__ int   s_ps[100];
  __shared__ float s_sc[100];
  // 4608 blocks; all 144 blocks of plane b=(t*4+g) land on XCD (b&7) so the
  // 2.36 MB idx1t slice + 1.18 MB qhalf g-slice stay resident in that XCD's L2.
  const int ib = blockIdx.x;
  const int xcd = ib & 7;
  const int sl = ib >> 3;              // 0..575
  const int b = xcd + 8 * (sl / 144);  // plane 0..31
  const int r0 = sl % 144;
  const int y = r0 / 3;
  const int xt = r0 - y * 3;
  const int t = b >> 2, g = b & 3;
  const int j = threadIdx.x;      // output channel 128+j
  const int x0 = xt * 16;
  const int tp = t * FN;

  // stage the 5x20 window's (source row, scale) pairs
  if (j < 100) {
    const int rr = j / 20, cc = j - rr * 20;
    const int yy = y - 2 + rr, xx = x0 - 2 + cc;
    int sv = 0; float sc = 0.f;
    if ((unsigned)yy < 48u && (unsigned)xx < 48u) {
      const int p = tp + yy * 48 + xx;
      sv = psrc[p]; sc = pscale[p];
    }
    s_ps[j] = sv; s_sc[j] = sc;
  }

  float w0[25], w1[25];
  {
    const float* wp = wtdw + (size_t)(128 + j) * 50;
#pragma unroll
    for (int p = 0; p < 25; ++p) { w0[p] = wp[p]; w1[p] = wp[25 + p]; }
  }
  float acc[16];
#pragma unroll
  for (int i2 = 0; i2 < 16; ++i2) acc[i2] = 0.f;
  const int cbase = g * 256 + 2 * j;
  __syncthreads();
#pragma unroll
  for (int r = 0; r < 5; ++r) {
    const int yy = y - 2 + r;
    if (yy < 0 || yy >= 48) continue;
#pragma unroll
    for (int cc2 = 0; cc2 < 20; ++cc2) {
      const int s2 = s_ps[r * 20 + cc2];
      const float sc = s_sc[r * 20 + cc2];
      const float2 v = *reinterpret_cast<const float2*>(idx1t + (((size_t)tp + s2) << 10) + cbase);
      const float vx = v.x * sc, vy = v.y * sc;
#pragma unroll
      for (int kx = 0; kx < 5; ++kx) {
        const int xo = cc2 - kx;
        if (xo >= 0 && xo < 16)
          acc[xo] = fmaf(vx, w0[r * 5 + kx], fmaf(vy, w1[r * 5 + kx], acc[xo]));
      }
    }
  }
  const float bb = btdw[128 + j];
#pragma unroll
  for (int xo = 0; xo < 16; ++xo) ch[xo][128 + j] = acc[xo] + bb;
#pragma unroll
  for (int xo = 0; xo < 16; ++xo)
    ch[xo][j] = qhalf[((size_t)g * FN + (y * 48 + x0 + xo)) * 128 + j];
  __syncthreads();

  const int lane = j & 63, wv = j >> 6;
  for (int p = wv; p < 16; p += 2) {
    float v0 = ch[p][lane], v1 = ch[p][lane + 64], v2 = ch[p][lane + 128], v3 = ch[p][lane + 192];
    float s = v0 + v1 + v2 + v3;
    float q = v0 * v0 + v1 * v1 + v2 * v2 + v3 * v3;
#pragma unroll
    for (int m = 1; m <= 32; m <<= 1) { s += __shfl_xor(s, m, 64); q += __shfl_xor(q, m, 64); }
    float mean = s * (1.0f / 256.0f);
    float var = q * (1.0f / 256.0f) - mean * mean;
    float rstd = rsqrtf(var + 1e-5f);
    float d0 = 0.f, d1 = 0.f;
#pragma unroll
    for (int k2 = 0; k2 < 4; k2++) {
      int c = lane + 64 * k2;
      float xv = (k2 == 0) ? v0 : (k2 == 1) ? v1 : (k2 == 2) ? v2 : v3;
      float xn = (xv - mean) * rstd * lng[c] + lnb[c];
      float ge = 0.5f * xn * (1.0f + erff(xn * 0.70710678118654752440f));
      d0 += ge * wtpw[c];
      d1 += ge * wtpw[256 + c];
    }
#pragma unroll
    for (int m = 1; m <= 32; m <<= 1) { d0 += __shfl_xor(d0, m, 64); d1 += __shfl_xor(d1, m, 64); }
    if (lane == 0) {
      float o0 = tanhf(d0) * (2.0f / 48.0f);
      float o1 = tanhf(d1) * (2.0f / 48.0f);
      int x = x0 + p;
      float ry = (0.5f + (float)y) / 48.0f * 2.0f - 1.0f;
      float rx = (0.5f + (float)x) / 48.0f * 2.0f - 1.0f;
      float pos0 = o0 + ry, pos1 = o1 + rx;   // gp = reversed
      float ix = (pos1 + 1.0f) * 0.5f * 47.0f;
      float iy = (pos0 + 1.0f) * 0.5f * 47.0f;
      float x0f = floorf(ix), y0f = floorf(iy);
      float wx = ix - x0f, wy = iy - y0f;
      int xi = (int)x0f, yi = (int)y0f;
      size_t base = ((size_t)b * FN + y * 48 + x) * 4;
#pragma unroll
      for (int c = 0; c < 4; c++) {
        int dy = c >> 1, dx = c & 1;
        int yy2 = yi + dy, xx2 = xi + dx;
        bool ok = ((unsigned)yy2 < 48u) && ((unsigned)xx2 < 48u);
        float wgt = (dy ? wy : 1.0f - wy) * (dx ? wx : 1.0f - wx);
        bsrc[base + c] = ok ? (yy2 * 48 + xx2) : -1;
        bw[base + c] = wgt;
      }
    }
  }
}

// ---------------- K6: mat einsum + max/argmax over t (indirect from idx1t) ----------------
__global__ __launch_bounds__(256) void k_mat(const float* __restrict__ idx1t,
                                             const int* __restrict__ psrc,
                                             const float* __restrict__ pscale,
                                             const float* __restrict__ cn,
                                             const int* __restrict__ bsrc,
                                             const float* __restrict__ bw,
                                             float* __restrict__ csoft,
                                             int* __restrict__ cidx) {
  __shared__ float red[8][4];
  const int f = blockIdx.x;
  const int tid = threadIdx.x;
  const int lane = tid & 63, w = tid >> 6;   // w == channel group gg
  const int coff = w * 256 + lane * 4;
  const float4 cnv = *reinterpret_cast<const float4*>(cn + (size_t)f * FL + coff);
#pragma unroll
  for (int t = 0; t < TT; t++) {
    const size_t mb = ((size_t)(t * 4 + w) * FN + f) * 4;
    const int4 cs = *reinterpret_cast<const int4*>(bsrc + mb);
    const float4 wv = *reinterpret_cast<const float4*>(bw + mb);
    const int tp = t * FN;
    const float* base = idx1t + ((size_t)tp << 10) + coff;
    float ax = 0.f, ay = 0.f, az = 0.f, aw = 0.f;
    if (cs.x >= 0) { const float wsc = wv.x * pscale[tp + cs.x];
      const float4 u = *reinterpret_cast<const float4*>(base + ((size_t)psrc[tp + cs.x] << 10));
      ax = fmaf(wsc, u.x, ax); ay = fmaf(wsc, u.y, ay); az = fmaf(wsc, u.z, az); aw = fmaf(wsc, u.w, aw); }
    if (cs.y >= 0) { const float wsc = wv.y * pscale[tp + cs.y];
      const float4 u = *reinterpret_cast<const float4*>(base + ((size_t)psrc[tp + cs.y] << 10));
      ax = fmaf(wsc, u.x, ax); ay = fmaf(wsc, u.y, ay); az = fmaf(wsc, u.z, az); aw = fmaf(wsc, u.w, aw); }
    if (cs.z >= 0) { const float wsc = wv.z * pscale[tp + cs.z];
      const float4 u = *reinterpret_cast<const float4*>(base + ((size_t)psrc[tp + cs.z] << 10));
      ax = fmaf(wsc, u.x, ax); ay = fmaf(wsc, u.y, ay); az = fmaf(wsc, u.z, az); aw = fmaf(wsc, u.w, aw); }
    if (cs.w >= 0) { const float wsc = wv.w * pscale[tp + cs.w];
      const float4 u = *reinterpret_cast<const float4*>(base + ((size_t)psrc[tp + cs.w] << 10));
      ax = fmaf(wsc, u.x, ax); ay = fmaf(wsc, u.y, ay); az = fmaf(wsc, u.z, az); aw = fmaf(wsc, u.w, aw); }
    float partial = ax * cnv.x + ay * cnv.y + az * cnv.z + aw * cnv.w;
#pragma unroll
    for (int m = 1; m <= 32; m <<= 1) partial += __shfl_xor(partial, m, 64);
    if (lane == 0) red[t][w] = partial;
  }
  __syncthreads();
  if (tid == 0) {
    float bestv = -INFINITY;
    int besti = 0;
#pragma unroll
    for (int t = 0; t < TT; t++) {
      float tot = red[t][0] + red[t][1] + red[t][2] + red[t][3];
      if (tot > bestv) { bestv = tot; besti = t; }
    }
    csoft[f] = bestv; cidx[f] = besti;
  }
}

// ---------------- K7: compose bilinear corners with nearest map at t=cidx ----------------
__global__ void k_comp(const int* __restrict__ bsrc, const float* __restrict__ bw,
                       const int* __restrict__ cidx, const int* __restrict__ srcmap,
                       int* __restrict__ csrc, float* __restrict__ cw) {
  int idx = blockIdx.x * 256 + threadIdx.x;  // f*4+g
  if (idx >= FN * 4) return;
  int f = idx >> 2, g = idx & 3;
  int t = cidx[f];
  int b = t * 4 + g;
  size_t mb = ((size_t)b * FN + f) * 4;
  size_t ob = (size_t)idx * 4;
#pragma unroll
  for (int c = 0; c < 4; c++) {
    int s = bsrc[mb + c];
    csrc[ob + c] = (s >= 0) ? srcmap[t * FN + s] : -1;
    cw[ob + c] = bw[mb + c];
  }
}

// ---------------- K8: fused nearest+bilinear+select of sparse sets (float4 stream) ----------------
__global__ __launch_bounds__(256) void k_sel(const float* __restrict__ s1,
                                             const float* __restrict__ s2,
                                             const float* __restrict__ s3,
                                             const int* __restrict__ cidx,
                                             const int* __restrict__ csrc,
                                             const float* __restrict__ cw,
                                             float* __restrict__ sel) {
  __shared__ float pl[4 * FN];   // 4 t-planes of this channel, 36,864 B
  const int cl = blockIdx.x, m = blockIdx.y;
  const float* sm = (m == 0) ? s1 : (m == 1) ? s2 : s3;
  const int g = cl >> 8;
  const int tid = threadIdx.x;
  float acc[9];
  int tsel[9];
  int4 cs[9];
  float4 wv[9];
#pragma unroll
  for (int it = 0; it < 9; it++) {
    int f = tid + 256 * it;
    tsel[it] = cidx[f];
    cs[it] = *reinterpret_cast<const int4*>(csrc + ((size_t)f * 4 + g) * 4);
    wv[it] = *reinterpret_cast<const float4*>(cw + ((size_t)f * 4 + g) * 4);
    acc[it] = 0.f;
  }
  float4* pl4 = reinterpret_cast<float4*>(pl);
  for (int half = 0; half < 2; half++) {
    __syncthreads();
#pragma unroll
    for (int j = 0; j < 9; j++) {             // 2304 float4 over 256 threads
      const int e = j * 256 + tid;
      const int tl = e / 576;                 // plane 0..3
      const int r = e - tl * 576;
      const float4* src4 = reinterpret_cast<const float4*>(sm + ((size_t)(half * 4 + tl) * FL + cl) * FN);
      pl4[e] = src4[r];
    }
    __syncthreads();
#pragma unroll
    for (int it = 0; it < 9; it++) {
      const int t = tsel[it] - half * 4;
      if (t >= 0 && t < 4) {
        float a = 0.f;
        if (cs[it].x >= 0) a += wv[it].x * pl[t * FN + cs[it].x];
        if (cs[it].y >= 0) a += wv[it].y * pl[t * FN + cs[it].y];
        if (cs[it].z >= 0) a += wv[it].z * pl[t * FN + cs[it].z];
        if (cs[it].w >= 0) a += wv[it].w * pl[t * FN + cs[it].w];
        acc[it] = a;
      }
    }
  }
  // re-pack through LDS for float4 row stores
  __syncthreads();
#pragma unroll
  for (int it = 0; it < 9; it++) pl[tid + 256 * it] = acc[it];
  __syncthreads();
  float4* orow = reinterpret_cast<float4*>(sel + ((size_t)m * FL + cl) * FN);
#pragma unroll
  for (int e = tid; e < 576; e += 256) orow[e] = pl4[e];
}

// ---------------- K9a: zero fin borders (halo ring) ----------------
__global__ void k_zb(unsigned int* __restrict__ fin_u) {
  int idx = blockIdx.x * 256 + threadIdx.x;
  if (idx >= 772 * 96) return;
  int bp = idx / 96, u = idx % 96;
  int yy, xx;
  if (bp < 194)      { yy = 0;   xx = bp; }
  else if (bp < 388) { yy = 193; xx = bp - 194; }
  else if (bp < 580) { yy = bp - 388 + 1; xx = 0; }
  else               { yy = bp - 580 + 1; xx = 193; }
  fin_u[((size_t)yy * 194 + xx) * 96 + u] = 0;
}

// ---------------- K9b: fold + concat -> bf16 channel-last padded fin[194][194][192] ----------------
__global__ __launch_bounds__(256) void k_fold2(const float* __restrict__ sel,
                                               ushort* __restrict__ fin) {
  __shared__ float ld[256 * 49];   // 256 cl_local x 48 f_local (pad 49)
  const int fy = blockIdx.x;
  const int m = blockIdx.y >> 2, c2t = blockIdx.y & 3;
  const int t = threadIdx.x;
  const float* sp = sel + ((size_t)m * 1024 + c2t * 256) * 2304 + fy * 48;
#pragma unroll
  for (int j = 0; j < 12; j++) {             // 3072 float4 = 256 rows x 12
    const int e = t + 256 * j;
    const int cl_l = e / 12, c4 = e % 12;
    const float4 v = *reinterpret_cast<const float4*>(sp + (size_t)cl_l * 2304 + c4 * 4);
    float* dr = &ld[cl_l * 49 + c4 * 4];
    dr[0] = v.x; dr[1] = v.y; dr[2] = v.z; dr[3] = v.w;
  }
  __syncthreads();
  const int ci0 = m * 64 + c2t * 16 + (t & 3) * 4;
  const int xb = t >> 2;           // 0..63
#pragma unroll
  for (int py = 0; py < 4; py++) {
    for (int jx = 0; jx < 3; jx++) {
      const int x = xb + 64 * jx;
      const int px = x & 3, fx = x >> 2;
      ushort4 v;
      ushort* vp = (ushort*)&v;
#pragma unroll
      for (int jj = 0; jj < 4; jj++) {
        int cl_l = ((t & 3) * 4 + jj) * 16 + py * 4 + px;
        vp[jj] = f2bf(ld[cl_l * 49 + fx]);
      }
      *reinterpret_cast<ushort4*>(fin + (((size_t)(fy * 4 + py + 1) * 194) + x + 1) * 192 + ci0) = v;
    }
  }
}

// ---------------- K9c: weights -> bf16 wb[co][tap][ci] ----------------
__global__ void k_wb(const float* __restrict__ wfus, ushort* __restrict__ wb) {
  int idx = blockIdx.x * 256 + threadIdx.x;   // over 64*9*96 ci-pairs
  if (idx >= 64 * 9 * 96) return;
  int cp = idx % 96, tap = (idx / 96) % 9, co = idx / (96 * 9);
  int ci = cp * 2;
  float a = wfus[((size_t)co * 192 + ci) * 9 + tap];
  float b = wfus[((size_t)co * 192 + ci + 1) * 9 + tap];
  unsigned int pk = (unsigned int)f2bf(a) | ((unsigned int)f2bf(b) << 16);
  reinterpret_cast<unsigned int*>(wb)[((size_t)co * 9 + tap) * 96 + cp] = pk;
}

// ---------------- K10: 3x3 fusion conv as bf16 MFMA implicit GEMM + *csoft_f + af ----------------
__global__ __launch_bounds__(256) void k_fus(const ushort* __restrict__ fin,
                                             const ushort* __restrict__ wb,
                                             const float* __restrict__ bfus,
                                             const float* __restrict__ csoft,
                                             const float* __restrict__ af,
                                             float* __restrict__ out) {
  const int y = blockIdx.x;
  const int wv = threadIdx.x >> 6;
  const int l = threadIdx.x & 63;
  const int ln = l & 15, qd = l >> 4;
  const int x0 = wv * 48;
  floatx4 acc[4][3];
#pragma unroll
  for (int a = 0; a < 4; a++)
#pragma unroll
    for (int b = 0; b < 3; b++) acc[a][b] = (floatx4){0.f, 0.f, 0.f, 0.f};

  const int koff = qd * 8;
  for (int tap = 0; tap < 9; tap++) {
    const int ky = tap / 3, kx = tap % 3;
    const ushort* brow = fin + ((size_t)(y + ky) * 194 + kx) * 192;
    const ushort* wrow = wb + (size_t)tap * 192;
#pragma unroll
    for (int c6 = 0; c6 < 6; c6++) {
      const int ci = c6 * 32 + koff;
      short8 A[4], B[3];
#pragma unroll
      for (int mt = 0; mt < 4; mt++)
        A[mt] = *reinterpret_cast<const short8*>(wrow + (size_t)(mt * 16 + ln) * 1728 + ci);
#pragma unroll
      for (int nt = 0; nt < 3; nt++)
        B[nt] = *reinterpret_cast<const short8*>(brow + (size_t)(x0 + nt * 16 + ln) * 192 + ci);
#pragma unroll
      for (int mt = 0; mt < 4; mt++)
#pragma unroll
        for (int nt = 0; nt < 3; nt++)
          acc[mt][nt] = __builtin_amdgcn_mfma_f32_16x16x32_bf16(A[mt], B[nt], acc[mt][nt], 0, 0, 0);
    }
  }
#pragma unroll
  for (int nt = 0; nt < 3; nt++) {
    const int x = x0 + nt * 16 + ln;
    const float cs = csoft[(y >> 2) * 48 + (x >> 2)];
#pragma unroll
    for (int mt = 0; mt < 4; mt++) {
#pragma unroll
      for (int r = 0; r < 4; r++) {
        const int co = mt * 16 + qd * 4 + r;
        const size_t oi = (size_t)co * 36864 + (size_t)y * 192 + x;
        out[oi] = (acc[mt][nt][r] + bfus[co]) * cs + af[oi];
      }
    }
  }
}

// ---------------- launcher ----------------
extern "C" void kernel_launch(void* const* d_in, const int* in_sizes, int n_in,
                              void* d_out, int out_size, void* d_ws, size_t ws_size,
                              hipStream_t stream) {
  const float* cf   = (const float*)d_in[0];
  const float* idx1 = (const float*)d_in[1];
  const float* af   = (const float*)d_in[2];
  const float* s1   = (const float*)d_in[3];
  const float* s2   = (const float*)d_in[4];
  const float* s3   = (const float*)d_in[5];
  const float* loc  = (const float*)d_in[6];
  const float* wtdw = (const float*)d_in[7];
  const float* btdw = (const float*)d_in[8];
  const float* lng  = (const float*)d_in[9];
  const float* lnb  = (const float*)d_in[10];
  const float* wtpw = (const float*)d_in[11];
  const float* wfus = (const float*)d_in[12];
  const float* bfus = (const float*)d_in[13];
  float* out = (float*)d_out;
  char* ws = (char*)d_ws;

  float* idx1t  = (float*)(ws + OFF_IDX1T);
  float* sel    = (float*)(ws + OFF_SEL);
  ushort* fin   = (ushort*)(ws + OFF_FIN);
  ushort* wb    = (ushort*)(ws + OFF_WB);
  float* norm2  = (float*)(ws + OFF_NORM2);
  int*   psrc   = (int*)(ws + OFF_PSRC);
  float* pscale = (float*)(ws + OFF_PSCALE);
  float* cn     = (float*)(ws + OFF_CN);
  float* qh     = (float*)(ws + OFF_QH);
  int*   srcmap = (int*)(ws + OFF_SRCMAP);
  int*   bsrc   = (int*)(ws + OFF_BSRC);
  float* bw     = (float*)(ws + OFF_BW);
  float* csoft  = (float*)(ws + OFF_CSOFT);
  int*   cidx   = (int*)(ws + OFF_CIDX);
  int*   csrc   = (int*)(ws + OFF_CSRC);
  float* cw     = (float*)(ws + OFF_CW);

  k_nearmap<<<72, 256, 0, stream>>>(loc, srcmap, norm2);
  k_transpose<<<dim3(16, 36, 8), 256, 0, stream>>>(idx1, idx1t, norm2);
  k_cn<<<2304, 256, 0, stream>>>(cf, cn);
  k_pos<<<72, 256, 0, stream>>>(srcmap, norm2, psrc, pscale);
  k_wb<<<216, 256, 0, stream>>>(wfus, wb);
  k_zb<<<290, 256, 0, stream>>>((unsigned int*)fin);
  k_qconv<<<576, 128, 0, stream>>>(cn, wtdw, btdw, qh);
  k_kconv_ln<<<4608, 128, 0, stream>>>(idx1t, psrc, pscale, wtdw, btdw, qh, lng, lnb, wtpw, bsrc, bw);
  k_mat<<<2304, 256, 0, stream>>>(idx1t, psrc, pscale, cn, bsrc, bw, csoft, cidx);
  k_comp<<<36, 256, 0, stream>>>(bsrc, bw, cidx, srcmap, csrc, cw);
  k_sel<<<dim3(1024, 3), 256, 0, stream>>>(s1, s2, s3, cidx, csrc, cw, sel);
  k_fold2<<<dim3(48, 12), 256, 0, stream>>>(sel, fin);
  k_fus<<<192, 256, 0, stream>>>(fin, wb, bfus, csoft, af, out);
}